// Round 1
// baseline (62.747 us; speedup 1.0000x reference)
//
#include <hip/hip_runtime.h>
#include <math.h>

#define Jn 161
#define Vn 131072
#define Kn 8
#define Bn 8
#define Pn 1127
#define NLOC 960   // P - 6 - J

struct Q  { float x, y, z, w; };
struct F3 { float x, y, z; };

__device__ __forceinline__ F3 cross3(F3 a, F3 b) {
    return F3{ a.y*b.z - a.z*b.y, a.z*b.x - a.x*b.z, a.x*b.y - a.y*b.x };
}
__device__ __forceinline__ Q qmul(Q a, Q b) {
    return Q{ a.w*b.x + a.x*b.w + a.y*b.z - a.z*b.y,
              a.w*b.y - a.x*b.z + a.y*b.w + a.z*b.x,
              a.w*b.z + a.x*b.y - a.y*b.x + a.z*b.w,
              a.w*b.w - a.x*b.x - a.y*b.y - a.z*b.z };
}
__device__ __forceinline__ F3 qrot(Q q, F3 v) {
    F3 qv{ q.x, q.y, q.z };
    F3 t = cross3(qv, v);
    t.x *= 2.f; t.y *= 2.f; t.z *= 2.f;
    F3 c = cross3(qv, t);
    return F3{ v.x + q.w*t.x + c.x, v.y + q.w*t.y + c.y, v.z + q.w*t.z + c.z };
}
__device__ __forceinline__ Q qfromxyz(float ex, float ey, float ez) {
    float sx = sinf(0.5f*ex), cx = cosf(0.5f*ex);
    float sy = sinf(0.5f*ey), cy = cosf(0.5f*ey);
    float sz = sinf(0.5f*ez), cz = cosf(0.5f*ez);
    return Q{ sx*cy*cz + cx*sy*sz,
              cx*sy*cz - sx*cy*sz,
              cx*cy*sz + sx*sy*cz,
              cx*cy*cz - sx*sy*sz };
}

// ---------------------------------------------------------------------------
// Kernel 0: recover JOINT_PARENTS from bind_state.
// bind_state = FK(transform_offsets), so parent(i) = argmin_p ||compose(bind[p], local_i) - bind[i]||.
// ---------------------------------------------------------------------------
__global__ __launch_bounds__(256) void k_parents(
    const float* __restrict__ toff, const float* __restrict__ joff,
    const float* __restrict__ jrot, const float* __restrict__ bind,
    int* __restrict__ parents)
{
    __shared__ float    loc[Jn][8];   // lt(3), lr(4), ls(1)
    __shared__ float    bnd[Jn][8];
    __shared__ unsigned slot[Jn];
    const int tid = threadIdx.x;

    for (int i = tid; i < Jn; i += blockDim.x) {
        slot[i] = 0xFFFFFFFFu;
        Q fx = qfromxyz(toff[i*7+3], toff[i*7+4], toff[i*7+5]);
        Q jr{ jrot[i*4+0], jrot[i*4+1], jrot[i*4+2], jrot[i*4+3] };
        Q lr = qmul(jr, fx);
        loc[i][0] = toff[i*7+0] + joff[i*3+0];
        loc[i][1] = toff[i*7+1] + joff[i*3+1];
        loc[i][2] = toff[i*7+2] + joff[i*3+2];
        loc[i][3] = lr.x; loc[i][4] = lr.y; loc[i][5] = lr.z; loc[i][6] = lr.w;
        loc[i][7] = exp2f(toff[i*7+6]);
        #pragma unroll
        for (int c = 0; c < 8; ++c) bnd[i][c] = bind[i*8 + c];
    }
    __syncthreads();

    for (int t = tid; t < Jn*Jn; t += blockDim.x) {
        int i = t / Jn;
        int p = t - i*Jn;
        if (i == 0 || p >= i) continue;
        Q  pr{ bnd[p][3], bnd[p][4], bnd[p][5], bnd[p][6] };
        float ps = bnd[p][7];
        Q  lr{ loc[i][3], loc[i][4], loc[i][5], loc[i][6] };
        Q  gr = qmul(pr, lr);
        F3 gt = qrot(pr, F3{ loc[i][0]*ps, loc[i][1]*ps, loc[i][2]*ps });
        gt.x += bnd[p][0]; gt.y += bnd[p][1]; gt.z += bnd[p][2];
        float gs = ps * loc[i][7];
        float err = 0.f, d;
        d = gr.x - bnd[i][3]; err += d*d;
        d = gr.y - bnd[i][4]; err += d*d;
        d = gr.z - bnd[i][5]; err += d*d;
        d = gr.w - bnd[i][6]; err += d*d;
        d = gt.x - bnd[i][0]; err += d*d;
        d = gt.y - bnd[i][1]; err += d*d;
        d = gt.z - bnd[i][2]; err += d*d;
        d = gs   - bnd[i][7]; err += d*d;
        unsigned pk = (__float_as_uint(err) & 0xFFFFFF00u) | (unsigned)p;
        atomicMin(&slot[i], pk);
    }
    __syncthreads();

    for (int i = tid; i < Jn; i += blockDim.x)
        parents[i] = (i == 0) ? -1 : (int)(slot[i] & 0xFFu);
}

// ---------------------------------------------------------------------------
// Kernel 1: params[b][p] = sum_q pose[b][q] * transform[p][q] + toff[p]
// One block (1 wave) per row p; coalesced row reads; butterfly reduce.
// ---------------------------------------------------------------------------
__global__ __launch_bounds__(64) void k_params(
    const float* __restrict__ gp, const float* __restrict__ lp,
    const float* __restrict__ sc, const float* __restrict__ T,
    const float* __restrict__ toff, float* __restrict__ params)
{
    const int p    = blockIdx.x;
    const int lane = threadIdx.x;
    const float* row = T + (size_t)p * Pn;

    float acc[Bn];
    #pragma unroll
    for (int b = 0; b < Bn; ++b) acc[b] = 0.f;

    for (int q = lane; q < Pn; q += 64) {
        float tv = row[q];
        #pragma unroll
        for (int b = 0; b < Bn; ++b) {
            float pv;
            if (q < 6)            pv = gp[b*6 + q];
            else if (q < 6+NLOC)  pv = lp[b*NLOC + (q-6)];
            else                  pv = sc[b*Jn + (q-6-NLOC)];
            acc[b] = fmaf(tv, pv, acc[b]);
        }
    }
    #pragma unroll
    for (int b = 0; b < Bn; ++b)
        #pragma unroll
        for (int o = 32; o > 0; o >>= 1)
            acc[b] += __shfl_xor(acc[b], o, 64);

    if (lane == 0) {
        float off = toff[p];
        #pragma unroll
        for (int b = 0; b < Bn; ++b)
            params[b*Pn + p] = acc[b] + off;
    }
}

// ---------------------------------------------------------------------------
// Kernel 2: FK (ancestor-chain walk, parallel over (b, joint)) + states_to_matrix.
// One block per batch b.
// ---------------------------------------------------------------------------
__global__ __launch_bounds__(192) void k_fk(
    const float* __restrict__ params, const float* __restrict__ joff,
    const float* __restrict__ jrot,   const float* __restrict__ bind,
    const int* __restrict__ parents,  float* __restrict__ mat)
{
    __shared__ float loc[Jn][8];
    __shared__ int   par[Jn];
    const int b   = blockIdx.x;
    const int tid = threadIdx.x;

    if (tid < Jn) {
        const int i = tid;
        par[i] = parents[i];
        const float* jp = params + b*Pn + i*7;
        Q fx = qfromxyz(jp[3], jp[4], jp[5]);
        Q jr{ jrot[i*4+0], jrot[i*4+1], jrot[i*4+2], jrot[i*4+3] };
        Q lr = qmul(jr, fx);
        loc[i][0] = jp[0] + joff[i*3+0];
        loc[i][1] = jp[1] + joff[i*3+1];
        loc[i][2] = jp[2] + joff[i*3+2];
        loc[i][3] = lr.x; loc[i][4] = lr.y; loc[i][5] = lr.z; loc[i][6] = lr.w;
        loc[i][7] = exp2f(jp[6]);
    }
    __syncthreads();

    if (tid < Jn) {
        const int i = tid;
        // accumulate global transform by walking ancestors: acc = L_j ∘ acc
        F3 at{ loc[i][0], loc[i][1], loc[i][2] };
        Q  ar{ loc[i][3], loc[i][4], loc[i][5], loc[i][6] };
        float as = loc[i][7];
        int j = par[i];
        while (j >= 0) {
            Q  lr{ loc[j][3], loc[j][4], loc[j][5], loc[j][6] };
            float ls = loc[j][7];
            F3 nt = qrot(lr, F3{ at.x*ls, at.y*ls, at.z*ls });
            at = F3{ nt.x + loc[j][0], nt.y + loc[j][1], nt.z + loc[j][2] };
            ar = qmul(lr, ar);
            as = ls * as;
            j = par[j];
        }

        // states_to_matrix
        const float* bv = bind + i*8;
        Q  br{ -bv[3], -bv[4], -bv[5], bv[6] };
        float bs = 1.f / bv[7];
        F3 btv = qrot(br, F3{ -bv[0], -bv[1], -bv[2] });
        btv.x *= bs; btv.y *= bs; btv.z *= bs;

        Q  tr = qmul(ar, br);
        float ts = as * bs;
        F3 tt = qrot(ar, F3{ btv.x*as, btv.y*as, btv.z*as });
        tt.x += at.x; tt.y += at.y; tt.z += at.z;

        float x = tr.x, y = tr.y, z = tr.z, w = tr.w;
        float twx = 2.f*x*w, twy = 2.f*y*w, twz = 2.f*z*w;
        float txx = 2.f*x*x, txy = 2.f*y*x, txz = 2.f*z*x;
        float tyy = 2.f*y*y, tyz = 2.f*z*y, tzz = 2.f*z*z;

        float* m = mat + (size_t)(b*Jn + i) * 12;
        m[0]  = (1.f - (tyy + tzz)) * ts;  // [0][0]
        m[1]  = (txy - twz) * ts;          // [0][1]
        m[2]  = (txz + twy) * ts;          // [0][2]
        m[3]  = tt.x;                      // [0][3]
        m[4]  = (txy + twz) * ts;          // [1][0]
        m[5]  = (1.f - (txx + tzz)) * ts;  // [1][1]
        m[6]  = (tyz - twx) * ts;          // [1][2]
        m[7]  = tt.y;                      // [1][3]
        m[8]  = (txz - twy) * ts;          // [2][0]
        m[9]  = (tyz + twx) * ts;          // [2][1]
        m[10] = (1.f - (txx + tyy)) * ts;  // [2][2]
        m[11] = tt.z;                      // [2][3]
    }
}

// ---------------------------------------------------------------------------
// Kernel 3: skinning. Thread per vertex, all 8 batches unrolled.
// Full matrix set (8*161*12 f32 = 61.8 KB) staged in LDS.
// ---------------------------------------------------------------------------
__global__ __launch_bounds__(256) void k_skin(
    const float* __restrict__ mat, const float* __restrict__ wts,
    const float* __restrict__ verts, const int* __restrict__ idx,
    float* __restrict__ out)
{
    __shared__ float4 smat[Bn*Jn*3];   // 3 float4 rows per (b, j)
    const int tid = threadIdx.x;

    const float4* gm = (const float4*)mat;
    #pragma unroll
    for (int t = tid; t < Bn*Jn*3; t += 256)
        smat[t] = gm[t];
    __syncthreads();

    const int v = blockIdx.x * 256 + tid;

    const int4*   ip = (const int4*)(idx) + v*2;
    const float4* wp = (const float4*)(wts) + v*2;
    int4   i0 = ip[0], i1 = ip[1];
    float4 w0 = wp[0], w1 = wp[1];

    const float vx = verts[v*3+0], vy = verts[v*3+1], vz = verts[v*3+2];

    int   jj[Kn] = { i0.x, i0.y, i0.z, i0.w, i1.x, i1.y, i1.z, i1.w };
    float ww[Kn] = { w0.x, w0.y, w0.z, w0.w, w1.x, w1.y, w1.z, w1.w };

    #pragma unroll
    for (int b = 0; b < Bn; ++b) {
        float a0 = 0.f, a1 = 0.f, a2 = 0.f;
        #pragma unroll
        for (int k = 0; k < Kn; ++k) {
            const int base = (b*Jn + jj[k]) * 3;
            float4 m0 = smat[base+0];
            float4 m1 = smat[base+1];
            float4 m2 = smat[base+2];
            float wk = ww[k];
            a0 = fmaf(wk, fmaf(m0.x, vx, fmaf(m0.y, vy, fmaf(m0.z, vz, m0.w))), a0);
            a1 = fmaf(wk, fmaf(m1.x, vx, fmaf(m1.y, vy, fmaf(m1.z, vz, m1.w))), a1);
            a2 = fmaf(wk, fmaf(m2.x, vx, fmaf(m2.y, vy, fmaf(m2.z, vz, m2.w))), a2);
        }
        float* o = out + ((size_t)b*Vn + v) * 3;
        o[0] = a0; o[1] = a1; o[2] = a2;
    }
}

// ---------------------------------------------------------------------------
extern "C" void kernel_launch(void* const* d_in, const int* in_sizes, int n_in,
                              void* d_out, int out_size, void* d_ws, size_t ws_size,
                              hipStream_t stream)
{
    (void)in_sizes; (void)n_in; (void)out_size; (void)ws_size;

    const float* gp    = (const float*)d_in[0];   // global_pose   [8,6]
    const float* lp    = (const float*)d_in[1];   // local_pose    [8,960]
    const float* sc    = (const float*)d_in[2];   // scale         [8,161]
    const float* T     = (const float*)d_in[3];   // transform     [1127,1127]
    const float* toff  = (const float*)d_in[4];   // transform_offsets [1127]
    const float* joff  = (const float*)d_in[5];   // joint_offset  [161,3]
    const float* jrot  = (const float*)d_in[6];   // joint_rotation[161,4]
    const float* bind  = (const float*)d_in[7];   // bind_state    [1,161,8]
    const float* wts   = (const float*)d_in[8];   // skin_weights  [131072,8]
    const float* verts = (const float*)d_in[9];   // mesh_vertices [131072,3]
    const int*   idx   = (const int*)d_in[10];    // skin_indices  [131072,8]
    float* out = (float*)d_out;

    char* ws = (char*)d_ws;
    int*   parents = (int*)ws;                    // 161 ints   @ 0
    float* params  = (float*)(ws + 4096);         // 8*1127 f32 @ 4096
    float* mat     = (float*)(ws + 49152);        // 8*161*12   @ 49152

    k_parents<<<1, 256, 0, stream>>>(toff, joff, jrot, bind, parents);
    k_params <<<Pn, 64, 0, stream>>>(gp, lp, sc, T, toff, params);
    k_fk     <<<Bn, 192, 0, stream>>>(params, joff, jrot, bind, parents, mat);
    k_skin   <<<Vn/256, 256, 0, stream>>>(mat, wts, verts, idx, out);
}

// Round 2
// 58.327 us; speedup vs baseline: 1.0758x; 1.0758x over previous
//
#include <hip/hip_runtime.h>
#include <hip/hip_fp16.h>
#include <math.h>

#define Jn 161
#define Vn 131072
#define Kn 8
#define Bn 8
#define Pn 1127
#define NLOC 960   // P - 6 - J
#define MATU (Bn*Jn*6)        // packed-f16 matrices, in uints (2 halves each)

struct Q  { float x, y, z, w; };
struct F3 { float x, y, z; };

__device__ __forceinline__ F3 cross3(F3 a, F3 b) {
    return F3{ a.y*b.z - a.z*b.y, a.z*b.x - a.x*b.z, a.x*b.y - a.y*b.x };
}
__device__ __forceinline__ Q qmul(Q a, Q b) {
    return Q{ a.w*b.x + a.x*b.w + a.y*b.z - a.z*b.y,
              a.w*b.y - a.x*b.z + a.y*b.w + a.z*b.x,
              a.w*b.z + a.x*b.y - a.y*b.x + a.z*b.w,
              a.w*b.w - a.x*b.x - a.y*b.y - a.z*b.z };
}
__device__ __forceinline__ F3 qrot(Q q, F3 v) {
    F3 qv{ q.x, q.y, q.z };
    F3 t = cross3(qv, v);
    t.x *= 2.f; t.y *= 2.f; t.z *= 2.f;
    F3 c = cross3(qv, t);
    return F3{ v.x + q.w*t.x + c.x, v.y + q.w*t.y + c.y, v.z + q.w*t.z + c.z };
}
__device__ __forceinline__ Q qfromxyz(float ex, float ey, float ez) {
    float sx = sinf(0.5f*ex), cx = cosf(0.5f*ex);
    float sy = sinf(0.5f*ey), cy = cosf(0.5f*ey);
    float sz = sinf(0.5f*ez), cz = cosf(0.5f*ez);
    return Q{ sx*cy*cz + cx*sy*sz,
              cx*sy*cz - sx*cy*sz,
              cx*cy*sz + sx*sy*cz,
              cx*cy*cz - sx*sy*sz };
}

__device__ __forceinline__ unsigned packh2(float a, float b) {
    unsigned lo = (unsigned)__half_as_ushort(__float2half_rn(a));
    unsigned hi = (unsigned)__half_as_ushort(__float2half_rn(b));
    return lo | (hi << 16);
}
__device__ __forceinline__ float2 unpackh2(unsigned u) {
    float2 r;
    r.x = __half2float(__ushort_as_half((unsigned short)(u & 0xFFFFu)));
    r.y = __half2float(__ushort_as_half((unsigned short)(u >> 16)));
    return r;
}

// ---------------------------------------------------------------------------
// Kernel 1: params[b][p] = sum_q pose[b][q] * transform[p][q] + toff[p]
// One block (1 wave) per row p; coalesced row reads; butterfly reduce.
// ---------------------------------------------------------------------------
__global__ __launch_bounds__(64) void k_params(
    const float* __restrict__ gp, const float* __restrict__ lp,
    const float* __restrict__ sc, const float* __restrict__ T,
    const float* __restrict__ toff, float* __restrict__ params)
{
    const int p    = blockIdx.x;
    const int lane = threadIdx.x;
    const float* row = T + (size_t)p * Pn;

    float acc[Bn];
    #pragma unroll
    for (int b = 0; b < Bn; ++b) acc[b] = 0.f;

    for (int q = lane; q < Pn; q += 64) {
        float tv = row[q];
        #pragma unroll
        for (int b = 0; b < Bn; ++b) {
            float pv;
            if (q < 6)            pv = gp[b*6 + q];
            else if (q < 6+NLOC)  pv = lp[b*NLOC + (q-6)];
            else                  pv = sc[b*Jn + (q-6-NLOC)];
            acc[b] = fmaf(tv, pv, acc[b]);
        }
    }
    #pragma unroll
    for (int b = 0; b < Bn; ++b)
        #pragma unroll
        for (int o = 32; o > 0; o >>= 1)
            acc[b] += __shfl_xor(acc[b], o, 64);

    if (lane == 0) {
        float off = toff[p];
        #pragma unroll
        for (int b = 0; b < Bn; ++b)
            params[b*Pn + p] = acc[b] + off;
    }
}

// ---------------------------------------------------------------------------
// Kernel 2 (fused): parents recovery + FK chain walk + states_to_matrix,
// output packed f16 matrices. One block per batch (parents work is redundant
// across the 8 blocks but runs in parallel — removes the serial k_parents).
// ---------------------------------------------------------------------------
__global__ __launch_bounds__(256) void k_fk(
    const float* __restrict__ params, const float* __restrict__ joff,
    const float* __restrict__ jrot,   const float* __restrict__ toff,
    const float* __restrict__ bind,   unsigned* __restrict__ mat16)
{
    __shared__ float    locB[Jn][8];  // bind-pose locals (from toff)
    __shared__ float    bnd[Jn][8];   // bind_state
    __shared__ float    loc[Jn][8];   // this batch's locals (from params)
    __shared__ unsigned slot[Jn];
    __shared__ int      par[Jn];
    const int b   = blockIdx.x;
    const int tid = threadIdx.x;

    if (tid < Jn) {
        const int i = tid;
        slot[i] = 0xFFFFFFFFu;
        // bind-pose locals
        {
            Q fx = qfromxyz(toff[i*7+3], toff[i*7+4], toff[i*7+5]);
            Q jr{ jrot[i*4+0], jrot[i*4+1], jrot[i*4+2], jrot[i*4+3] };
            Q lr = qmul(jr, fx);
            locB[i][0] = toff[i*7+0] + joff[i*3+0];
            locB[i][1] = toff[i*7+1] + joff[i*3+1];
            locB[i][2] = toff[i*7+2] + joff[i*3+2];
            locB[i][3] = lr.x; locB[i][4] = lr.y; locB[i][5] = lr.z; locB[i][6] = lr.w;
            locB[i][7] = exp2f(toff[i*7+6]);
        }
        #pragma unroll
        for (int c = 0; c < 8; ++c) bnd[i][c] = bind[i*8 + c];
        // batch locals
        {
            const float* jp = params + b*Pn + i*7;
            Q fx = qfromxyz(jp[3], jp[4], jp[5]);
            Q jr{ jrot[i*4+0], jrot[i*4+1], jrot[i*4+2], jrot[i*4+3] };
            Q lr = qmul(jr, fx);
            loc[i][0] = jp[0] + joff[i*3+0];
            loc[i][1] = jp[1] + joff[i*3+1];
            loc[i][2] = jp[2] + joff[i*3+2];
            loc[i][3] = lr.x; loc[i][4] = lr.y; loc[i][5] = lr.z; loc[i][6] = lr.w;
            loc[i][7] = exp2f(jp[6]);
        }
    }
    __syncthreads();

    // parents: argmin_p || compose(bind[p], bindlocal_i) - bind[i] ||
    for (int t = tid; t < Jn*Jn; t += 256) {
        const int i = t / Jn;
        const int p = t - i*Jn;
        if (i == 0 || p >= i) continue;
        Q  pr{ bnd[p][3], bnd[p][4], bnd[p][5], bnd[p][6] };
        float ps = bnd[p][7];
        Q  lr{ locB[i][3], locB[i][4], locB[i][5], locB[i][6] };
        Q  gr = qmul(pr, lr);
        F3 gt = qrot(pr, F3{ locB[i][0]*ps, locB[i][1]*ps, locB[i][2]*ps });
        gt.x += bnd[p][0]; gt.y += bnd[p][1]; gt.z += bnd[p][2];
        float gs = ps * locB[i][7];
        float err = 0.f, d;
        d = gr.x - bnd[i][3]; err += d*d;
        d = gr.y - bnd[i][4]; err += d*d;
        d = gr.z - bnd[i][5]; err += d*d;
        d = gr.w - bnd[i][6]; err += d*d;
        d = gt.x - bnd[i][0]; err += d*d;
        d = gt.y - bnd[i][1]; err += d*d;
        d = gt.z - bnd[i][2]; err += d*d;
        d = gs   - bnd[i][7]; err += d*d;
        unsigned pk = (__float_as_uint(err) & 0xFFFFFF00u) | (unsigned)p;
        atomicMin(&slot[i], pk);
    }
    __syncthreads();
    if (tid < Jn)
        par[tid] = (tid == 0) ? -1 : (int)(slot[tid] & 0xFFu);
    __syncthreads();

    if (tid < Jn) {
        const int i = tid;
        // accumulate global transform by walking ancestors: acc = L_j ∘ acc
        F3 at{ loc[i][0], loc[i][1], loc[i][2] };
        Q  ar{ loc[i][3], loc[i][4], loc[i][5], loc[i][6] };
        float as = loc[i][7];
        int j = par[i];
        while (j >= 0) {
            Q  lr{ loc[j][3], loc[j][4], loc[j][5], loc[j][6] };
            float ls = loc[j][7];
            F3 nt = qrot(lr, F3{ at.x*ls, at.y*ls, at.z*ls });
            at = F3{ nt.x + loc[j][0], nt.y + loc[j][1], nt.z + loc[j][2] };
            ar = qmul(lr, ar);
            as = ls * as;
            j = par[j];
        }

        // states_to_matrix
        const float* bv = bind + i*8;
        Q  br{ -bv[3], -bv[4], -bv[5], bv[6] };
        float bs = 1.f / bv[7];
        F3 btv = qrot(br, F3{ -bv[0], -bv[1], -bv[2] });
        btv.x *= bs; btv.y *= bs; btv.z *= bs;

        Q  tr = qmul(ar, br);
        float ts = as * bs;
        F3 tt = qrot(ar, F3{ btv.x*as, btv.y*as, btv.z*as });
        tt.x += at.x; tt.y += at.y; tt.z += at.z;

        float x = tr.x, y = tr.y, z = tr.z, w = tr.w;
        float twx = 2.f*x*w, twy = 2.f*y*w, twz = 2.f*z*w;
        float txx = 2.f*x*x, txy = 2.f*y*x, txz = 2.f*z*x;
        float tyy = 2.f*y*y, tyz = 2.f*z*y, tzz = 2.f*z*z;

        float m0  = (1.f - (tyy + tzz)) * ts;  // row0
        float m1  = (txy - twz) * ts;
        float m2  = (txz + twy) * ts;
        float m3  = tt.x;
        float m4  = (txy + twz) * ts;          // row1
        float m5  = (1.f - (txx + tzz)) * ts;
        float m6  = (tyz - twx) * ts;
        float m7  = tt.y;
        float m8  = (txz - twy) * ts;          // row2
        float m9  = (tyz + twx) * ts;
        float m10 = (1.f - (txx + tyy)) * ts;
        float m11 = tt.z;

        unsigned* o = mat16 + (size_t)(b*Jn + i) * 6;
        o[0] = packh2(m0,  m1);
        o[1] = packh2(m2,  m3);
        o[2] = packh2(m4,  m5);
        o[3] = packh2(m6,  m7);
        o[4] = packh2(m8,  m9);
        o[5] = packh2(m10, m11);
    }
}

// ---------------------------------------------------------------------------
// Kernel 3: skinning. Thread per vertex, 8 batches unrolled in registers.
// Packed-f16 matrices (24 B each, 30.9 KB total) staged in LDS; gathers are
// 3x ds_read_b64 at 24 B stride (even-dword starts -> bank-balanced floor).
// ---------------------------------------------------------------------------
__global__ __launch_bounds__(256) void k_skin(
    const unsigned* __restrict__ mat16, const float* __restrict__ wts,
    const float* __restrict__ verts, const int* __restrict__ idx,
    float* __restrict__ out)
{
    __shared__ unsigned sm[MATU];       // 7728 uints = 30912 B
    const int tid = threadIdx.x;

    // linear staged copy (uint4): 7728/4 = 1932 chunks
    {
        const uint4* g4 = (const uint4*)mat16;
        uint4* s4 = (uint4*)sm;
        for (int t = tid; t < MATU/4; t += 256) s4[t] = g4[t];
    }
    __syncthreads();

    const int v = blockIdx.x * 256 + tid;

    const int4*   ip = (const int4*)(idx) + v*2;
    const float4* wp = (const float4*)(wts) + v*2;
    int4   i0 = ip[0], i1 = ip[1];
    float4 w0 = wp[0], w1 = wp[1];

    const float vx = verts[v*3+0], vy = verts[v*3+1], vz = verts[v*3+2];

    int   jj[Kn] = { i0.x, i0.y, i0.z, i0.w, i1.x, i1.y, i1.z, i1.w };
    float ww[Kn] = { w0.x, w0.y, w0.z, w0.w, w1.x, w1.y, w1.z, w1.w };

    #pragma unroll
    for (int b = 0; b < Bn; ++b) {
        float a0 = 0.f, a1 = 0.f, a2 = 0.f;
        #pragma unroll
        for (int k = 0; k < Kn; ++k) {
            const int base = (b*Jn + jj[k]) * 6;
            uint2 q0 = *(const uint2*)&sm[base];      // m0 m1 | m2 m3
            uint2 q1 = *(const uint2*)&sm[base+2];    // m4 m5 | m6 m7
            uint2 q2 = *(const uint2*)&sm[base+4];    // m8 m9 | m10 m11
            float2 ma = unpackh2(q0.x), mb = unpackh2(q0.y);
            float2 mc = unpackh2(q1.x), md = unpackh2(q1.y);
            float2 me = unpackh2(q2.x), mf = unpackh2(q2.y);
            float wk = ww[k];
            a0 = fmaf(wk, fmaf(ma.x, vx, fmaf(ma.y, vy, fmaf(mb.x, vz, mb.y))), a0);
            a1 = fmaf(wk, fmaf(mc.x, vx, fmaf(mc.y, vy, fmaf(md.x, vz, md.y))), a1);
            a2 = fmaf(wk, fmaf(me.x, vx, fmaf(me.y, vy, fmaf(mf.x, vz, mf.y))), a2);
        }
        float* o = out + ((size_t)b*Vn + v) * 3;
        o[0] = a0; o[1] = a1; o[2] = a2;
    }
}

// ---------------------------------------------------------------------------
extern "C" void kernel_launch(void* const* d_in, const int* in_sizes, int n_in,
                              void* d_out, int out_size, void* d_ws, size_t ws_size,
                              hipStream_t stream)
{
    (void)in_sizes; (void)n_in; (void)out_size; (void)ws_size;

    const float* gp    = (const float*)d_in[0];   // global_pose   [8,6]
    const float* lp    = (const float*)d_in[1];   // local_pose    [8,960]
    const float* sc    = (const float*)d_in[2];   // scale         [8,161]
    const float* T     = (const float*)d_in[3];   // transform     [1127,1127]
    const float* toff  = (const float*)d_in[4];   // transform_offsets [1127]
    const float* joff  = (const float*)d_in[5];   // joint_offset  [161,3]
    const float* jrot  = (const float*)d_in[6];   // joint_rotation[161,4]
    const float* bind  = (const float*)d_in[7];   // bind_state    [1,161,8]
    const float* wts   = (const float*)d_in[8];   // skin_weights  [131072,8]
    const float* verts = (const float*)d_in[9];   // mesh_vertices [131072,3]
    const int*   idx   = (const int*)d_in[10];    // skin_indices  [131072,8]
    float* out = (float*)d_out;

    char* ws = (char*)d_ws;
    float*    params = (float*)ws;                 // 8*1127 f32  @ 0     (36 KB)
    unsigned* mat16  = (unsigned*)(ws + 40960);    // 7728 uints  @ 40960 (31 KB)

    k_params<<<Pn, 64, 0, stream>>>(gp, lp, sc, T, toff, params);
    k_fk    <<<Bn, 256, 0, stream>>>(params, joff, jrot, toff, bind, mat16);
    k_skin  <<<Vn/256, 256, 0, stream>>>(mat16, wts, verts, idx, out);
}

// Round 3
// 30.452 us; speedup vs baseline: 2.0606x; 1.9154x over previous
//
#include <hip/hip_runtime.h>
#include <hip/hip_fp16.h>
#include <math.h>

#define Jn 161
#define Vn 131072
#define Kn 8
#define Bn 8
#define Pn 1127
#define NLOC 960   // P - 6 - J
#define MATU (Bn*Jn*6)        // packed-f16 matrices, in uints (2 halves each)

struct Q  { float x, y, z, w; };
struct F3 { float x, y, z; };

__device__ __forceinline__ F3 cross3(F3 a, F3 b) {
    return F3{ a.y*b.z - a.z*b.y, a.z*b.x - a.x*b.z, a.x*b.y - a.y*b.x };
}
__device__ __forceinline__ Q qmul(Q a, Q b) {
    return Q{ a.w*b.x + a.x*b.w + a.y*b.z - a.z*b.y,
              a.w*b.y - a.x*b.z + a.y*b.w + a.z*b.x,
              a.w*b.z + a.x*b.y - a.y*b.x + a.z*b.w,
              a.w*b.w - a.x*b.x - a.y*b.y - a.z*b.z };
}
__device__ __forceinline__ F3 qrot(Q q, F3 v) {
    F3 qv{ q.x, q.y, q.z };
    F3 t = cross3(qv, v);
    t.x *= 2.f; t.y *= 2.f; t.z *= 2.f;
    F3 c = cross3(qv, t);
    return F3{ v.x + q.w*t.x + c.x, v.y + q.w*t.y + c.y, v.z + q.w*t.z + c.z };
}
__device__ __forceinline__ Q qfromxyz(float ex, float ey, float ez) {
    float sx = sinf(0.5f*ex), cx = cosf(0.5f*ex);
    float sy = sinf(0.5f*ey), cy = cosf(0.5f*ey);
    float sz = sinf(0.5f*ez), cz = cosf(0.5f*ez);
    return Q{ sx*cy*cz + cx*sy*sz,
              cx*sy*cz - sx*cy*sz,
              cx*cy*sz + sx*sy*cz,
              cx*cy*cz - sx*sy*sz };
}

__device__ __forceinline__ unsigned packh2(float a, float b) {
    unsigned lo = (unsigned)__half_as_ushort(__float2half_rn(a));
    unsigned hi = (unsigned)__half_as_ushort(__float2half_rn(b));
    return lo | (hi << 16);
}
__device__ __forceinline__ float2 unpackh2(unsigned u) {
    float2 r;
    r.x = __half2float(__ushort_as_half((unsigned short)(u & 0xFFFFu)));
    r.y = __half2float(__ushort_as_half((unsigned short)(u >> 16)));
    return r;
}

// ---------------------------------------------------------------------------
// Kernel 1 (fused front): blocks 0..Jn-1 recover parent(i); blocks Jn..Jn+Pn-1
// compute params row (GEMV). Parents path: lanes test candidate parents
// p = lane + 64k, packed (err|p) shfl-min reduce — no LDS, no atomics.
// ---------------------------------------------------------------------------
__global__ __launch_bounds__(64) void k_front(
    const float* __restrict__ gp, const float* __restrict__ lp,
    const float* __restrict__ sc, const float* __restrict__ T,
    const float* __restrict__ toff, const float* __restrict__ joff,
    const float* __restrict__ jrot, const float* __restrict__ bind,
    float* __restrict__ params, int* __restrict__ parents)
{
    const int blk  = blockIdx.x;
    const int lane = threadIdx.x;

    if (blk < Jn) {
        // ---- parents for joint i = blk ----
        const int i = blk;
        if (i == 0) { if (lane == 0) parents[0] = -1; return; }

        // local_i at bind pose (all lanes redundantly — SIMT-free)
        Q fx = qfromxyz(toff[i*7+3], toff[i*7+4], toff[i*7+5]);
        Q jr{ jrot[i*4+0], jrot[i*4+1], jrot[i*4+2], jrot[i*4+3] };
        Q lr = qmul(jr, fx);
        const float l0 = toff[i*7+0] + joff[i*3+0];
        const float l1 = toff[i*7+1] + joff[i*3+1];
        const float l2 = toff[i*7+2] + joff[i*3+2];
        const float lsc = exp2f(toff[i*7+6]);

        float bi[8];
        #pragma unroll
        for (int c = 0; c < 8; ++c) bi[c] = bind[i*8+c];

        unsigned best = 0xFFFFFFFFu;
        for (int p = lane; p < i; p += 64) {
            const float* bp = bind + p*8;
            Q  pr{ bp[3], bp[4], bp[5], bp[6] };
            float ps = bp[7];
            Q  gr = qmul(pr, lr);
            F3 gt = qrot(pr, F3{ l0*ps, l1*ps, l2*ps });
            gt.x += bp[0]; gt.y += bp[1]; gt.z += bp[2];
            float gs = ps * lsc;
            float err = 0.f, d;
            d = gr.x - bi[3]; err += d*d;
            d = gr.y - bi[4]; err += d*d;
            d = gr.z - bi[5]; err += d*d;
            d = gr.w - bi[6]; err += d*d;
            d = gt.x - bi[0]; err += d*d;
            d = gt.y - bi[1]; err += d*d;
            d = gt.z - bi[2]; err += d*d;
            d = gs   - bi[7]; err += d*d;
            unsigned pk = (__float_as_uint(err) & 0xFFFFFF00u) | (unsigned)p;
            best = best < pk ? best : pk;
        }
        #pragma unroll
        for (int o = 32; o > 0; o >>= 1) {
            unsigned other = __shfl_xor(best, o, 64);
            best = best < other ? best : other;
        }
        if (lane == 0) parents[i] = (int)(best & 0xFFu);
        return;
    }

    // ---- params row p = blk - Jn ----
    const int p = blk - Jn;
    const float* row = T + (size_t)p * Pn;

    float acc[Bn];
    #pragma unroll
    for (int b = 0; b < Bn; ++b) acc[b] = 0.f;

    for (int q = lane; q < Pn; q += 64) {
        float tv = row[q];
        #pragma unroll
        for (int b = 0; b < Bn; ++b) {
            float pv;
            if (q < 6)            pv = gp[b*6 + q];
            else if (q < 6+NLOC)  pv = lp[b*NLOC + (q-6)];
            else                  pv = sc[b*Jn + (q-6-NLOC)];
            acc[b] = fmaf(tv, pv, acc[b]);
        }
    }
    #pragma unroll
    for (int b = 0; b < Bn; ++b)
        #pragma unroll
        for (int o = 32; o > 0; o >>= 1)
            acc[b] += __shfl_xor(acc[b], o, 64);

    if (lane == 0) {
        float off = toff[p];
        #pragma unroll
        for (int b = 0; b < Bn; ++b)
            params[b*Pn + p] = acc[b] + off;
    }
}

// ---------------------------------------------------------------------------
// Kernel 2: FK chain walk + states_to_matrix -> packed f16. Block per batch.
// LDS rows padded to 9 dwords (gcd(9,32)=1 -> conflict-free lane access).
// ---------------------------------------------------------------------------
__global__ __launch_bounds__(192) void k_fk(
    const float* __restrict__ params, const float* __restrict__ joff,
    const float* __restrict__ jrot,   const float* __restrict__ bind,
    const int* __restrict__ parents,  unsigned* __restrict__ mat16)
{
    __shared__ float loc[Jn][9];
    __shared__ int   par[Jn];
    const int b   = blockIdx.x;
    const int tid = threadIdx.x;

    if (tid < Jn) {
        const int i = tid;
        par[i] = parents[i];
        const float* jp = params + b*Pn + i*7;
        Q fx = qfromxyz(jp[3], jp[4], jp[5]);
        Q jr{ jrot[i*4+0], jrot[i*4+1], jrot[i*4+2], jrot[i*4+3] };
        Q lr = qmul(jr, fx);
        loc[i][0] = jp[0] + joff[i*3+0];
        loc[i][1] = jp[1] + joff[i*3+1];
        loc[i][2] = jp[2] + joff[i*3+2];
        loc[i][3] = lr.x; loc[i][4] = lr.y; loc[i][5] = lr.z; loc[i][6] = lr.w;
        loc[i][7] = exp2f(jp[6]);
    }
    __syncthreads();

    if (tid < Jn) {
        const int i = tid;
        F3 at{ loc[i][0], loc[i][1], loc[i][2] };
        Q  ar{ loc[i][3], loc[i][4], loc[i][5], loc[i][6] };
        float as = loc[i][7];
        int j = par[i];
        while (j >= 0) {
            Q  lr{ loc[j][3], loc[j][4], loc[j][5], loc[j][6] };
            float ls = loc[j][7];
            F3 nt = qrot(lr, F3{ at.x*ls, at.y*ls, at.z*ls });
            at = F3{ nt.x + loc[j][0], nt.y + loc[j][1], nt.z + loc[j][2] };
            ar = qmul(lr, ar);
            as = ls * as;
            j = par[j];
        }

        // states_to_matrix
        const float* bv = bind + i*8;
        Q  br{ -bv[3], -bv[4], -bv[5], bv[6] };
        float bs = 1.f / bv[7];
        F3 btv = qrot(br, F3{ -bv[0], -bv[1], -bv[2] });
        btv.x *= bs; btv.y *= bs; btv.z *= bs;

        Q  tr = qmul(ar, br);
        float ts = as * bs;
        F3 tt = qrot(ar, F3{ btv.x*as, btv.y*as, btv.z*as });
        tt.x += at.x; tt.y += at.y; tt.z += at.z;

        float x = tr.x, y = tr.y, z = tr.z, w = tr.w;
        float twx = 2.f*x*w, twy = 2.f*y*w, twz = 2.f*z*w;
        float txx = 2.f*x*x, txy = 2.f*y*x, txz = 2.f*z*x;
        float tyy = 2.f*y*y, tyz = 2.f*z*y, tzz = 2.f*z*z;

        float m0  = (1.f - (tyy + tzz)) * ts;
        float m1  = (txy - twz) * ts;
        float m2  = (txz + twy) * ts;
        float m3  = tt.x;
        float m4  = (txy + twz) * ts;
        float m5  = (1.f - (txx + tzz)) * ts;
        float m6  = (tyz - twx) * ts;
        float m7  = tt.y;
        float m8  = (txz - twy) * ts;
        float m9  = (tyz + twx) * ts;
        float m10 = (1.f - (txx + tyy)) * ts;
        float m11 = tt.z;

        unsigned* o = mat16 + (size_t)(b*Jn + i) * 6;
        o[0] = packh2(m0,  m1);
        o[1] = packh2(m2,  m3);
        o[2] = packh2(m4,  m5);
        o[3] = packh2(m6,  m7);
        o[4] = packh2(m8,  m9);
        o[5] = packh2(m10, m11);
    }
}

// ---------------------------------------------------------------------------
// Kernel 3: skinning. Thread per vertex, 8 batches unrolled in registers.
// Packed-f16 matrices (24 B each, 30.9 KB total) staged in LDS.
// ---------------------------------------------------------------------------
__global__ __launch_bounds__(256) void k_skin(
    const unsigned* __restrict__ mat16, const float* __restrict__ wts,
    const float* __restrict__ verts, const int* __restrict__ idx,
    float* __restrict__ out)
{
    __shared__ unsigned sm[MATU];       // 7728 uints = 30912 B
    const int tid = threadIdx.x;

    {
        const uint4* g4 = (const uint4*)mat16;
        uint4* s4 = (uint4*)sm;
        for (int t = tid; t < MATU/4; t += 256) s4[t] = g4[t];
    }
    __syncthreads();

    const int v = blockIdx.x * 256 + tid;

    const int4*   ip = (const int4*)(idx) + v*2;
    const float4* wp = (const float4*)(wts) + v*2;
    int4   i0 = ip[0], i1 = ip[1];
    float4 w0 = wp[0], w1 = wp[1];

    const float vx = verts[v*3+0], vy = verts[v*3+1], vz = verts[v*3+2];

    int   jj[Kn] = { i0.x, i0.y, i0.z, i0.w, i1.x, i1.y, i1.z, i1.w };
    float ww[Kn] = { w0.x, w0.y, w0.z, w0.w, w1.x, w1.y, w1.z, w1.w };

    #pragma unroll
    for (int b = 0; b < Bn; ++b) {
        float a0 = 0.f, a1 = 0.f, a2 = 0.f;
        #pragma unroll
        for (int k = 0; k < Kn; ++k) {
            const int base = (b*Jn + jj[k]) * 6;
            uint2 q0 = *(const uint2*)&sm[base];
            uint2 q1 = *(const uint2*)&sm[base+2];
            uint2 q2 = *(const uint2*)&sm[base+4];
            float2 ma = unpackh2(q0.x), mb = unpackh2(q0.y);
            float2 mc = unpackh2(q1.x), md = unpackh2(q1.y);
            float2 me = unpackh2(q2.x), mf = unpackh2(q2.y);
            float wk = ww[k];
            a0 = fmaf(wk, fmaf(ma.x, vx, fmaf(ma.y, vy, fmaf(mb.x, vz, mb.y))), a0);
            a1 = fmaf(wk, fmaf(mc.x, vx, fmaf(mc.y, vy, fmaf(md.x, vz, md.y))), a1);
            a2 = fmaf(wk, fmaf(me.x, vx, fmaf(me.y, vy, fmaf(mf.x, vz, mf.y))), a2);
        }
        float* o = out + ((size_t)b*Vn + v) * 3;
        o[0] = a0; o[1] = a1; o[2] = a2;
    }
}

// ---------------------------------------------------------------------------
extern "C" void kernel_launch(void* const* d_in, const int* in_sizes, int n_in,
                              void* d_out, int out_size, void* d_ws, size_t ws_size,
                              hipStream_t stream)
{
    (void)in_sizes; (void)n_in; (void)out_size; (void)ws_size;

    const float* gp    = (const float*)d_in[0];   // global_pose   [8,6]
    const float* lp    = (const float*)d_in[1];   // local_pose    [8,960]
    const float* sc    = (const float*)d_in[2];   // scale         [8,161]
    const float* T     = (const float*)d_in[3];   // transform     [1127,1127]
    const float* toff  = (const float*)d_in[4];   // transform_offsets [1127]
    const float* joff  = (const float*)d_in[5];   // joint_offset  [161,3]
    const float* jrot  = (const float*)d_in[6];   // joint_rotation[161,4]
    const float* bind  = (const float*)d_in[7];   // bind_state    [1,161,8]
    const float* wts   = (const float*)d_in[8];   // skin_weights  [131072,8]
    const float* verts = (const float*)d_in[9];   // mesh_vertices [131072,3]
    const int*   idx   = (const int*)d_in[10];    // skin_indices  [131072,8]
    float* out = (float*)d_out;

    char* ws = (char*)d_ws;
    float*    params  = (float*)ws;                 // 8*1127 f32  @ 0     (36 KB)
    unsigned* mat16   = (unsigned*)(ws + 40960);    // 7728 uints  @ 40960 (31 KB)
    int*      parents = (int*)(ws + 73728);         // 161 ints    @ 72 KB

    k_front<<<Jn + Pn, 64, 0, stream>>>(gp, lp, sc, T, toff, joff, jrot, bind, params, parents);
    k_fk   <<<Bn, 192, 0, stream>>>(params, joff, jrot, bind, parents, mat16);
    k_skin <<<Vn/256, 256, 0, stream>>>(mat16, wts, verts, idx, out);
}